// Round 1
// baseline (268.594 us; speedup 1.0000x reference)
//
#include <hip/hip_runtime.h>
#include <hip/hip_cooperative_groups.h>

namespace cg = cooperative_groups;

// ---------------------------------------------------------------------------
// BatchRelationalModule: b=16, c=64, L=256, F=64
// Round 7: FUSE ALL THREE KERNELS into one cooperative launch.
// Evidence: top-5 dispatches are all 256MiB harness poison-fills (~40.5us @
// 83% HBM peak), one per iteration; none of our kernels exceeds 40.4us, yet
// 113us total >> ~15us of modeled inner-loop work. The residual is
// per-dispatch fixed cost (launch ramps, inter-kernel drains, tiny-grid
// tails). One dispatch removes two kernel boundaries AND makes our kernel
// visible in next round's top-5 profile.
// Also: per-wave LDS slices instead of LDS atomicAdd epilogue; phase-C
// reduction parallelized over 256 threads; f-network matvecs vectorized.
// ---------------------------------------------------------------------------

typedef short s8v __attribute__((ext_vector_type(8)));   // 8 x bf16 (4 VGPR)
typedef short s4v __attribute__((ext_vector_type(4)));   // 4 x bf16 (2 VGPR)
typedef float f4v __attribute__((ext_vector_type(4)));   // 4 x f32  (4 VGPR)

#define KEEP(x) asm volatile("" : "+v"(x))   // opaque: forbids remat/sink

#define MFMA16(a, b, c) __builtin_amdgcn_mfma_f32_16x16x16bf16_1k(a, b, c, 0, 0, 0)

__device__ __forceinline__ short bfr(float v) {
  return __builtin_bit_cast(short, (__bf16)v);           // fp32 -> bf16 (RNE)
}
__device__ __forceinline__ f4v relu4(f4v v) {
  f4v z = {0.f, 0.f, 0.f, 0.f};
  return __builtin_elementwise_max(v, z);
}
__device__ __forceinline__ s8v cvt8(f4v a, f4v b) {
  s8v r;
  r[0] = bfr(a[0]); r[1] = bfr(a[1]); r[2] = bfr(a[2]); r[3] = bfr(a[3]);
  r[4] = bfr(b[0]); r[5] = bfr(b[1]); r[6] = bfr(b[2]); r[7] = bfr(b[3]);
  return r;
}
__device__ __forceinline__ s4v cvt4(f4v a) {
  s4v r;
  r[0] = bfr(a[0]); r[1] = bfr(a[1]); r[2] = bfr(a[2]); r[3] = bfr(a[3]);
  return r;
}
__device__ __forceinline__ f4v ldf4(const float* p) {
  return *(const f4v*)p;
}

// ---------------------------------------------------------------------------
// Fused kernel. grid (32,16) x 256 thr, cooperative, 2 blocks/CU (=512 co-res).
// Phase A: A/B' precompute (each block: 8 l's of one b).
// Phase B: pair loop (identical structure to round-6 k_main).
// Phase C: partial reduction + f-network (first 16 blocks).
// LDS: 8960 floats = 35.84 KB -> 4 blocks/CU by LDS, 2 by launch_bounds. OK.
// ---------------------------------------------------------------------------
__global__ __launch_bounds__(256, 2) void k_fused(
    const float* __restrict__ x, const float* __restrict__ Wg0,
    const float* __restrict__ bg0, const float* __restrict__ Wg1,
    const float* __restrict__ bg1, const float* __restrict__ Wg2,
    const float* __restrict__ bg2, const float* __restrict__ Wp,
    const float* __restrict__ bp, const float* __restrict__ Wo,
    const float* __restrict__ bo, float* __restrict__ out,
    float* __restrict__ Ag, float* __restrict__ Bg,
    float* __restrict__ Part) {
  __shared__ __align__(16) float LDS[8960];   // union of all phases
  const int t = threadIdx.x;
  const int bx = blockIdx.x;   // 0..31
  const int by = blockIdx.y;   // 0..15 (= batch)
  cg::grid_group grid = cg::this_grid();

  // ============================ Phase A ============================
  {
    float* ws = LDS;          // [64][131] padded Wg0
    float* xs = LDS + 8384;   // [64][9]  padded x-tile
    const int b = by, l0 = bx * 8;
    for (int i = t; i < 64 * 130; i += 256) {
      int f = i / 130, d = i - f * 130;
      ws[f * 131 + d] = Wg0[i];
    }
    for (int i = t; i < 512; i += 256) {
      int ch = i >> 3, li = i & 7;
      xs[ch * 9 + li] = x[b * 16384 + ch * 256 + l0 + li];
    }
    __syncthreads();
    const int f = t & 63;
    const int w = t >> 6;
    float aA0 = 0.f, aA1 = 0.f, aB0 = 0.f, aB1 = 0.f;
    for (int d = 0; d < 64; ++d) {
      float wa = ws[f * 131 + d];
      float wb = ws[f * 131 + 65 + d];
      float x0 = xs[d * 9 + w];        // broadcast (w uniform per wave)
      float x1 = xs[d * 9 + w + 4];
      aA0 += x0 * wa; aA1 += x1 * wa;
      aB0 += x0 * wb; aB1 += x1 * wb;
    }
    const float wca = ws[f * 131 + 64];
    const float wcb = ws[f * 131 + 129];
    const float bias = bg0[f];
    const int la = l0 + w, lb = l0 + w + 4;
    Ag[(b * 256 + la) * 64 + f] = aA0 + (float)la * wca;
    Bg[(b * 256 + la) * 64 + f] = aB0 + (float)la * wcb + bias;
    Ag[(b * 256 + lb) * 64 + f] = aA1 + (float)lb * wca;
    Bg[(b * 256 + lb) * 64 + f] = aB1 + (float)lb * wcb + bias;
  }
  __threadfence();
  grid.sync();

  // ============================ Phase B ============================
  {
    float* Bs = LDS;             // [32][64] = 8 KB
    float* WaveS = LDS + 2048;   // [4][64] per-wave partials (no atomics)
    const int wid = t >> 6;
    const int lane = t & 63;
    const int mm = lane & 15;
    const int quad = lane >> 4;
    const int b = by;
    const int blkx = bx;                  // 0..31
    const int qq = blkx & 3;
    const int p0 = (blkx >> 2) * 32;
    const int q0 = (qq * 4 + wid) * 16;

    // ---- stage B'[32 rows] (8 KB) into LDS, coalesced dwordx4 ----
    {
      const f4v* Bb4 = (const f4v*)(Bg + (b * 256 + p0) * 64);
      ((f4v*)Bs)[t] = Bb4[t];
      ((f4v*)Bs)[t + 256] = Bb4[t + 256];
    }

    // ---- A rows pinned: A[q0+mm][f = kh*32 + quad*8 + j] ----
    const float* Arow = Ag + (b * 256 + q0 + mm) * 64;
    f4v af0 = ldf4(Arow + quad * 8);
    f4v af1 = ldf4(Arow + quad * 8 + 4);
    f4v af2 = ldf4(Arow + 32 + quad * 8);
    f4v af3 = ldf4(Arow + 36 + quad * 8);

    // ---- layer-1 weights, K32 A-operand; layer-2 weights, K16 A-operand ----
    s8v W1f[4][2];
    s4v W2f[4][4];
    f4v c1i[4], c2i[4];
#pragma unroll
    for (int gt = 0; gt < 4; ++gt) {
      c1i[gt] = ldf4(bg1 + gt * 16 + quad * 4);
      c2i[gt] = ldf4(bg2 + gt * 16 + quad * 4);
#pragma unroll
      for (int kh = 0; kh < 2; ++kh) {
        const float* r1 = Wg1 + (gt * 16 + mm) * 64 + kh * 32 + quad * 8;
        W1f[gt][kh] = cvt8(ldf4(r1), ldf4(r1 + 4));
      }
#pragma unroll
      for (int kt = 0; kt < 4; ++kt) {
        const float* r2 = Wg2 + (gt * 16 + mm) * 64 + kt * 16 + quad * 4;
        W2f[gt][kt] = cvt4(ldf4(r2));
      }
    }
#pragma unroll
    for (int gt = 0; gt < 4; ++gt) {
      KEEP(W1f[gt][0]); KEEP(W1f[gt][1]);
      KEEP(W2f[gt][0]); KEEP(W2f[gt][1]); KEEP(W2f[gt][2]); KEEP(W2f[gt][3]);
      KEEP(c1i[gt]); KEEP(c2i[gt]);
    }
    KEEP(af0); KEEP(af1); KEEP(af2); KEEP(af3);

    __syncthreads();   // Bs staged

    f4v cs[4] = {{0.f,0.f,0.f,0.f},{0.f,0.f,0.f,0.f},
                 {0.f,0.f,0.f,0.f},{0.f,0.f,0.f,0.f}};

    // prefetch B'-frag for p = p0 (quad-broadcast ds_read_b128)
    f4v bq0 = ldf4(Bs + quad * 8);
    f4v bq1 = ldf4(Bs + quad * 8 + 4);
    f4v bq2 = ldf4(Bs + 32 + quad * 8);
    f4v bq3 = ldf4(Bs + 36 + quad * 8);

    for (int ip = 0; ip < 32; ++ip) {
      const float* bn = Bs + ((ip < 31) ? ip + 1 : 31) * 64;
      f4v bn0 = ldf4(bn + quad * 8);
      f4v bn1 = ldf4(bn + quad * 8 + 4);
      f4v bn2 = ldf4(bn + 32 + quad * 8);
      f4v bn3 = ldf4(bn + 36 + quad * 8);

      // ---- X fragment: X[q=mm][f] = relu(A+B') ----
      s8v x0 = cvt8(relu4(af0 + bq0), relu4(af1 + bq1));
      s8v x1 = cvt8(relu4(af2 + bq2), relu4(af3 + bq3));

      // ---- layer 1 + direct layer 2 (no LDS between) ----
      s4v pk[4];
#pragma unroll
      for (int gt = 0; gt < 4; ++gt) {
        f4v a = c1i[gt];
        a = __builtin_amdgcn_mfma_f32_16x16x32_bf16(W1f[gt][0], x0, a, 0, 0, 0);
        a = __builtin_amdgcn_mfma_f32_16x16x32_bf16(W1f[gt][1], x1, a, 0, 0, 0);
        pk[gt] = cvt4(relu4(a));
      }
#pragma unroll
      for (int ot = 0; ot < 4; ++ot) {
        f4v a = c2i[ot];
        a = MFMA16(W2f[ot][0], pk[0], a);
        a = MFMA16(W2f[ot][1], pk[1], a);
        a = MFMA16(W2f[ot][2], pk[2], a);
        a = MFMA16(W2f[ot][3], pk[3], a);
        cs[ot] += relu4(a);    // lane: o = ot*16+quad*4+r, q = mm
      }

      bq0 = bn0; bq1 = bn1; bq2 = bn2; bq3 = bn3;
    }

    // ---- reduce over q (mm lanes) -> per-wave LDS slice (NO atomics) ----
#pragma unroll
    for (int ot = 0; ot < 4; ++ot) {
#pragma unroll
      for (int r = 0; r < 4; ++r) {
        float v = cs[ot][r];
        v += __shfl_xor(v, 1);
        v += __shfl_xor(v, 2);
        v += __shfl_xor(v, 4);
        v += __shfl_xor(v, 8);
        if (mm == 0) WaveS[wid * 64 + ot * 16 + quad * 4 + r] = v;
      }
    }
    __syncthreads();
    if (t < 64) {
      float s = WaveS[t] + WaveS[64 + t] + WaveS[128 + t] + WaveS[192 + t];
      Part[(b * 32 + blkx) * 64 + t] = s;   // distinct slot, no contention
    }
  }
  __threadfence();
  grid.sync();

  // ============================ Phase C ============================
  if (by == 0 && bx < 16) {
    const int b = bx;
    const int o = t & 63, jw = t >> 6;
    // 256-thread parallel reduction of the 32 partials
    float s = 0.f;
    const float* Pb = Part + b * 2048;
#pragma unroll
    for (int j = 0; j < 8; ++j) s += Pb[(jw * 8 + j) * 64 + o];
    LDS[jw * 64 + o] = s;
    __syncthreads();
    if (t < 64) {
      float sum = LDS[t] + LDS[64 + t] + LDS[128 + t] + LDS[192 + t];
      LDS[256 + t] = sum;                       // sv
    }
    __syncthreads();
    if (t < 64) {
      float acc = bp[t];
#pragma unroll
      for (int g4 = 0; g4 < 16; ++g4) {
        f4v wv = ldf4(Wp + t * 64 + g4 * 4);
        f4v xv = ldf4(&LDS[256 + g4 * 4]);
        acc += wv[0] * xv[0] + wv[1] * xv[1] + wv[2] * xv[2] + wv[3] * xv[3];
      }
      LDS[320 + t] = fmaxf(acc, 0.f);           // tv
    }
    __syncthreads();
    if (t < 64) {
      float o2 = bo[t];
#pragma unroll
      for (int g4 = 0; g4 < 16; ++g4) {
        f4v wv = ldf4(Wo + t * 64 + g4 * 4);
        f4v xv = ldf4(&LDS[320 + g4 * 4]);
        o2 += wv[0] * xv[0] + wv[1] * xv[1] + wv[2] * xv[2] + wv[3] * xv[3];
      }
      out[b * 64 + t] = o2;
    }
  }
}

// ---------------------------------------------------------------------------
// Legacy 3-kernel fallback (round-6 verified path) in case the cooperative
// launch is rejected (returns hipError_t, checked at launch time).
// ---------------------------------------------------------------------------
__global__ __launch_bounds__(256) void k_pre(
    const float* __restrict__ x, const float* __restrict__ Wg0,
    const float* __restrict__ bg0, float* __restrict__ Ag,
    float* __restrict__ Bg) {
  __shared__ float ws[64 * 131];
  __shared__ float xs[64 * 17];

  const int t = threadIdx.x;
  const int b = blockIdx.x >> 4;
  const int l0 = (blockIdx.x & 15) * 16;

  for (int i = t; i < 64 * 130; i += 256) {
    int f = i / 130, d = i - f * 130;
    ws[f * 131 + d] = Wg0[i];
  }
  for (int i = t; i < 64 * 16; i += 256) {
    int ch = i >> 4, li = i & 15;
    xs[ch * 17 + li] = x[b * 16384 + ch * 256 + l0 + li];
  }
  __syncthreads();

  const int f = t & 63;
  const int w = t >> 6;
  float accA[4] = {0.f, 0.f, 0.f, 0.f};
  float accB[4] = {0.f, 0.f, 0.f, 0.f};
  for (int d = 0; d < 64; ++d) {
    float wa = ws[f * 131 + d];
    float wb = ws[f * 131 + 65 + d];
#pragma unroll
    for (int i = 0; i < 4; ++i) {
      float xv = xs[d * 17 + w + 4 * i];
      accA[i] += xv * wa;
      accB[i] += xv * wb;
    }
  }
  const float wca = ws[f * 131 + 64];
  const float wcb = ws[f * 131 + 129];
  const float bias = bg0[f];
#pragma unroll
  for (int i = 0; i < 4; ++i) {
    int l = l0 + w + 4 * i;
    Ag[(b * 256 + l) * 64 + f] = accA[i] + (float)l * wca;
    Bg[(b * 256 + l) * 64 + f] = accB[i] + (float)l * wcb + bias;
  }
}

__global__ __launch_bounds__(256, 2) void k_main(
    const float* __restrict__ Ag, const float* __restrict__ Bg,
    const float* __restrict__ Wg1, const float* __restrict__ bg1,
    const float* __restrict__ Wg2, const float* __restrict__ bg2,
    float* __restrict__ Part) {
  __shared__ __align__(16) float Bs[32 * 64];
  __shared__ float WaveS[4 * 64];

  const int t = threadIdx.x;
  const int wid = t >> 6;
  const int lane = t & 63;
  const int mm = lane & 15;
  const int quad = lane >> 4;
  const int b = blockIdx.y;
  const int blkx = blockIdx.x;
  const int qq = blkx & 3;
  const int p0 = (blkx >> 2) * 32;
  const int q0 = (qq * 4 + wid) * 16;

  {
    const f4v* Bb4 = (const f4v*)(Bg + (b * 256 + p0) * 64);
    ((f4v*)Bs)[t] = Bb4[t];
    ((f4v*)Bs)[t + 256] = Bb4[t + 256];
  }

  const float* Arow = Ag + (b * 256 + q0 + mm) * 64;
  f4v af0 = ldf4(Arow + quad * 8);
  f4v af1 = ldf4(Arow + quad * 8 + 4);
  f4v af2 = ldf4(Arow + 32 + quad * 8);
  f4v af3 = ldf4(Arow + 36 + quad * 8);

  s8v W1f[4][2];
  s4v W2f[4][4];
  f4v c1i[4], c2i[4];
#pragma unroll
  for (int gt = 0; gt < 4; ++gt) {
    c1i[gt] = ldf4(bg1 + gt * 16 + quad * 4);
    c2i[gt] = ldf4(bg2 + gt * 16 + quad * 4);
#pragma unroll
    for (int kh = 0; kh < 2; ++kh) {
      const float* r1 = Wg1 + (gt * 16 + mm) * 64 + kh * 32 + quad * 8;
      W1f[gt][kh] = cvt8(ldf4(r1), ldf4(r1 + 4));
    }
#pragma unroll
    for (int kt = 0; kt < 4; ++kt) {
      const float* r2 = Wg2 + (gt * 16 + mm) * 64 + kt * 16 + quad * 4;
      W2f[gt][kt] = cvt4(ldf4(r2));
    }
  }
#pragma unroll
  for (int gt = 0; gt < 4; ++gt) {
    KEEP(W1f[gt][0]); KEEP(W1f[gt][1]);
    KEEP(W2f[gt][0]); KEEP(W2f[gt][1]); KEEP(W2f[gt][2]); KEEP(W2f[gt][3]);
    KEEP(c1i[gt]); KEEP(c2i[gt]);
  }
  KEEP(af0); KEEP(af1); KEEP(af2); KEEP(af3);

  __syncthreads();

  f4v cs[4] = {{0.f,0.f,0.f,0.f},{0.f,0.f,0.f,0.f},
               {0.f,0.f,0.f,0.f},{0.f,0.f,0.f,0.f}};

  f4v bq0 = ldf4(Bs + quad * 8);
  f4v bq1 = ldf4(Bs + quad * 8 + 4);
  f4v bq2 = ldf4(Bs + 32 + quad * 8);
  f4v bq3 = ldf4(Bs + 36 + quad * 8);

  for (int ip = 0; ip < 32; ++ip) {
    const float* bn = Bs + ((ip < 31) ? ip + 1 : 31) * 64;
    f4v bn0 = ldf4(bn + quad * 8);
    f4v bn1 = ldf4(bn + quad * 8 + 4);
    f4v bn2 = ldf4(bn + 32 + quad * 8);
    f4v bn3 = ldf4(bn + 36 + quad * 8);

    s8v x0 = cvt8(relu4(af0 + bq0), relu4(af1 + bq1));
    s8v x1 = cvt8(relu4(af2 + bq2), relu4(af3 + bq3));

    s4v pk[4];
#pragma unroll
    for (int gt = 0; gt < 4; ++gt) {
      f4v a = c1i[gt];
      a = __builtin_amdgcn_mfma_f32_16x16x32_bf16(W1f[gt][0], x0, a, 0, 0, 0);
      a = __builtin_amdgcn_mfma_f32_16x16x32_bf16(W1f[gt][1], x1, a, 0, 0, 0);
      pk[gt] = cvt4(relu4(a));
    }
#pragma unroll
    for (int ot = 0; ot < 4; ++ot) {
      f4v a = c2i[ot];
      a = MFMA16(W2f[ot][0], pk[0], a);
      a = MFMA16(W2f[ot][1], pk[1], a);
      a = MFMA16(W2f[ot][2], pk[2], a);
      a = MFMA16(W2f[ot][3], pk[3], a);
      cs[ot] += relu4(a);
    }

    bq0 = bn0; bq1 = bn1; bq2 = bn2; bq3 = bn3;
  }

#pragma unroll
  for (int ot = 0; ot < 4; ++ot) {
#pragma unroll
    for (int r = 0; r < 4; ++r) {
      float v = cs[ot][r];
      v += __shfl_xor(v, 1);
      v += __shfl_xor(v, 2);
      v += __shfl_xor(v, 4);
      v += __shfl_xor(v, 8);
      if (mm == 0) WaveS[wid * 64 + ot * 16 + quad * 4 + r] = v;
    }
  }
  __syncthreads();
  if (t < 64) {
    float s = WaveS[t] + WaveS[64 + t] + WaveS[128 + t] + WaveS[192 + t];
    Part[(b * 32 + blkx) * 64 + t] = s;
  }
}

__global__ __launch_bounds__(64) void k_final(
    const float* __restrict__ Part, const float* __restrict__ Wp,
    const float* __restrict__ bp, const float* __restrict__ Wo,
    const float* __restrict__ bo, float* __restrict__ out) {
  __shared__ float sv[64], tv[64];
  const int b = blockIdx.x, t = threadIdx.x;
  float s = 0.f;
  const float* Pb = Part + b * 32 * 64;
#pragma unroll
  for (int j = 0; j < 32; ++j) s += Pb[j * 64 + t];
  sv[t] = s;
  __syncthreads();
  float acc = bp[t];
  for (int g = 0; g < 64; ++g) acc += sv[g] * Wp[t * 64 + g];
  tv[t] = fmaxf(acc, 0.f);
  __syncthreads();
  float o = bo[t];
  for (int f = 0; f < 64; ++f) o += tv[f] * Wo[t * 64 + f];
  out[b * 64 + t] = o;
}

// ---------------------------------------------------------------------------
extern "C" void kernel_launch(void* const* d_in, const int* in_sizes, int n_in,
                              void* d_out, int out_size, void* d_ws, size_t ws_size,
                              hipStream_t stream) {
  const float* x   = (const float*)d_in[0];
  const float* Wg0 = (const float*)d_in[1];
  const float* bg0 = (const float*)d_in[2];
  const float* Wg1 = (const float*)d_in[3];
  const float* bg1 = (const float*)d_in[4];
  const float* Wg2 = (const float*)d_in[5];
  const float* bg2 = (const float*)d_in[6];
  const float* Wp  = (const float*)d_in[7];
  const float* bp  = (const float*)d_in[8];
  const float* Wo  = (const float*)d_in[9];
  const float* bo  = (const float*)d_in[10];
  float* out = (float*)d_out;

  float* Ag   = (float*)d_ws;            // [16][256][64] fp32 = 1 MB
  float* Bg   = Ag + 16 * 256 * 64;      // [16][256][64] fp32 = 1 MB
  float* Part = Bg + 16 * 256 * 64;      // [16][32][64] fp32 = 128 KB

  void* args[] = {
      (void*)&x,  (void*)&Wg0, (void*)&bg0, (void*)&Wg1, (void*)&bg1,
      (void*)&Wg2, (void*)&bg2, (void*)&Wp, (void*)&bp, (void*)&Wo,
      (void*)&bo, (void*)&out, (void*)&Ag, (void*)&Bg, (void*)&Part};
  hipError_t err = hipLaunchCooperativeKernel(
      (const void*)k_fused, dim3(32, 16, 1), dim3(256, 1, 1), (void**)args, 0,
      stream);
  if (err != hipSuccess) {
    // fallback: round-6 verified 3-kernel path
    k_pre<<<256, 256, 0, stream>>>(x, Wg0, bg0, Ag, Bg);
    k_main<<<dim3(32, 16), 256, 0, stream>>>(Ag, Bg, Wg1, bg1, Wg2, bg2, Part);
    k_final<<<16, 64, 0, stream>>>(Part, Wp, bp, Wo, bo, out);
  }
}

// Round 2
// 172.443 us; speedup vs baseline: 1.5576x; 1.5576x over previous
//
#include <hip/hip_runtime.h>

// ---------------------------------------------------------------------------
// BatchRelationalModule: b=16, c=64, L=256, F=64
// Round 8: REVERT cooperative fusion (round 7: grid.sync across 8 non-coherent
// XCD L2s cost ~150us; k_fused=188us @ 9% VALUBusy). Decomposition from r7:
// harness-fixed floor ~81us (2x 256MiB poison fills @ 83% HBM peak), our 3
// kernels ~32us, launch gaps ~0 in the captured graph. So: shrink kernel time.
// Evidence: fused phase-B VALU-busy ~17us vs ~6-7us modeled issue time =>
// dependency-chain stalls at 2 waves/SIMD. Fix: 4 blocks/CU for k_main
// (grid 64x16, 16 p/block, VGPR 104 <= 128, LDS 5KB). Same total work,
// 2x latency hiding. k_final widened to 256 thr + vectorized matvecs.
// ---------------------------------------------------------------------------

typedef short s8v __attribute__((ext_vector_type(8)));   // 8 x bf16 (4 VGPR)
typedef short s4v __attribute__((ext_vector_type(4)));   // 4 x bf16 (2 VGPR)
typedef float f4v __attribute__((ext_vector_type(4)));   // 4 x f32  (4 VGPR)

#define KEEP(x) asm volatile("" : "+v"(x))   // opaque: forbids remat/sink

#define MFMA16(a, b, c) __builtin_amdgcn_mfma_f32_16x16x16bf16_1k(a, b, c, 0, 0, 0)

__device__ __forceinline__ short bfr(float v) {
  return __builtin_bit_cast(short, (__bf16)v);           // fp32 -> bf16 (RNE)
}
__device__ __forceinline__ f4v relu4(f4v v) {
  f4v z = {0.f, 0.f, 0.f, 0.f};
  return __builtin_elementwise_max(v, z);
}
__device__ __forceinline__ s8v cvt8(f4v a, f4v b) {
  s8v r;
  r[0] = bfr(a[0]); r[1] = bfr(a[1]); r[2] = bfr(a[2]); r[3] = bfr(a[3]);
  r[4] = bfr(b[0]); r[5] = bfr(b[1]); r[6] = bfr(b[2]); r[7] = bfr(b[3]);
  return r;
}
__device__ __forceinline__ s4v cvt4(f4v a) {
  s4v r;
  r[0] = bfr(a[0]); r[1] = bfr(a[1]); r[2] = bfr(a[2]); r[3] = bfr(a[3]);
  return r;
}
__device__ __forceinline__ f4v ldf4(const float* p) {
  return *(const f4v*)p;
}

// ---------------------------------------------------------------------------
// Kernel 1: precompute A and B' (fp32). Unchanged (verified, ~2-4 us).
// ---------------------------------------------------------------------------
__global__ __launch_bounds__(256) void k_pre(
    const float* __restrict__ x, const float* __restrict__ Wg0,
    const float* __restrict__ bg0, float* __restrict__ Ag,
    float* __restrict__ Bg) {
  __shared__ float ws[64 * 131];
  __shared__ float xs[64 * 17];

  const int t = threadIdx.x;
  const int b = blockIdx.x >> 4;
  const int l0 = (blockIdx.x & 15) * 16;

  for (int i = t; i < 64 * 130; i += 256) {
    int f = i / 130, d = i - f * 130;
    ws[f * 131 + d] = Wg0[i];
  }
  for (int i = t; i < 64 * 16; i += 256) {
    int ch = i >> 4, li = i & 15;
    xs[ch * 17 + li] = x[b * 16384 + ch * 256 + l0 + li];
  }
  __syncthreads();

  const int f = t & 63;
  const int w = t >> 6;
  float accA[4] = {0.f, 0.f, 0.f, 0.f};
  float accB[4] = {0.f, 0.f, 0.f, 0.f};
  for (int d = 0; d < 64; ++d) {
    float wa = ws[f * 131 + d];
    float wb = ws[f * 131 + 65 + d];
#pragma unroll
    for (int i = 0; i < 4; ++i) {
      float xv = xs[d * 17 + w + 4 * i];
      accA[i] += xv * wa;
      accB[i] += xv * wb;
    }
  }
  const float wca = ws[f * 131 + 64];
  const float wcb = ws[f * 131 + 129];
  const float bias = bg0[f];
#pragma unroll
  for (int i = 0; i < 4; ++i) {
    int l = l0 + w + 4 * i;
    Ag[(b * 256 + l) * 64 + f] = accA[i] + (float)l * wca;
    Bg[(b * 256 + l) * 64 + f] = accB[i] + (float)l * wcb + bias;
  }
}

// ---------------------------------------------------------------------------
// Kernel 2: pair loop. grid (64, 16) x 256 thr => 1024 blocks = 4 blocks/CU
// (was 2). 16 p-rows per block. Per p: B'-frag (LDS broadcast) ->
// X=relu(A+B') -> layer1 = 2x mfma16x16x32 (bias in C) -> relu/pack ->
// layer2 = 4x mfma16x16x16 direct chaining -> relu -> accumulate.
// Epilogue: per-wave LDS slices (no atomics) -> distinct global slot.
// ---------------------------------------------------------------------------
__global__ __launch_bounds__(256, 4) void k_main(
    const float* __restrict__ Ag, const float* __restrict__ Bg,
    const float* __restrict__ Wg1, const float* __restrict__ bg1,
    const float* __restrict__ Wg2, const float* __restrict__ bg2,
    float* __restrict__ Part) {
  __shared__ __align__(16) float Bs[16 * 64];   // 4 KB
  __shared__ float WaveS[4 * 64];               // 1 KB

  const int t = threadIdx.x;
  const int wid = t >> 6;
  const int lane = t & 63;
  const int mm = lane & 15;
  const int quad = lane >> 4;
  const int b = blockIdx.y;
  const int blkx = blockIdx.x;          // 0..63
  const int qq = blkx & 3;
  const int p0 = (blkx >> 2) * 16;      // 16 p-groups of 16 rows
  const int q0 = (qq * 4 + wid) * 16;

  // ---- stage B'[16 rows] (4 KB) into LDS, coalesced dwordx4 ----
  {
    const f4v* Bb4 = (const f4v*)(Bg + (b * 256 + p0) * 64);
    ((f4v*)Bs)[t] = Bb4[t];
  }

  // ---- A rows pinned: A[q0+mm][f = kh*32 + quad*8 + j] ----
  const float* Arow = Ag + (b * 256 + q0 + mm) * 64;
  f4v af0 = ldf4(Arow + quad * 8);
  f4v af1 = ldf4(Arow + quad * 8 + 4);
  f4v af2 = ldf4(Arow + 32 + quad * 8);
  f4v af3 = ldf4(Arow + 36 + quad * 8);

  // ---- layer-1 weights, K32 A-operand: W1[gt*16+mm][kh*32+quad*8+j] ----
  s8v W1f[4][2];
  // ---- layer-2 weights, K16 A-operand: W2[ot*16+mm][gt*16+quad*4+i] ----
  s4v W2f[4][4];
  f4v c1i[4], c2i[4];
#pragma unroll
  for (int gt = 0; gt < 4; ++gt) {
    c1i[gt] = ldf4(bg1 + gt * 16 + quad * 4);
    c2i[gt] = ldf4(bg2 + gt * 16 + quad * 4);
#pragma unroll
    for (int kh = 0; kh < 2; ++kh) {
      const float* r1 = Wg1 + (gt * 16 + mm) * 64 + kh * 32 + quad * 8;
      W1f[gt][kh] = cvt8(ldf4(r1), ldf4(r1 + 4));
    }
#pragma unroll
    for (int kt = 0; kt < 4; ++kt) {
      const float* r2 = Wg2 + (gt * 16 + mm) * 64 + kt * 16 + quad * 4;
      W2f[gt][kt] = cvt4(ldf4(r2));
    }
  }
  // Pin loop-invariants in registers (defeat remat/sink).
#pragma unroll
  for (int gt = 0; gt < 4; ++gt) {
    KEEP(W1f[gt][0]); KEEP(W1f[gt][1]);
    KEEP(W2f[gt][0]); KEEP(W2f[gt][1]); KEEP(W2f[gt][2]); KEEP(W2f[gt][3]);
    KEEP(c1i[gt]); KEEP(c2i[gt]);
  }
  KEEP(af0); KEEP(af1); KEEP(af2); KEEP(af3);

  __syncthreads();   // Bs staged

  f4v cs[4] = {{0.f,0.f,0.f,0.f},{0.f,0.f,0.f,0.f},
               {0.f,0.f,0.f,0.f},{0.f,0.f,0.f,0.f}};

  // prefetch B'-frag for p = p0 (quad-broadcast ds_read_b128)
  f4v bq0 = ldf4(Bs + quad * 8);
  f4v bq1 = ldf4(Bs + quad * 8 + 4);
  f4v bq2 = ldf4(Bs + 32 + quad * 8);
  f4v bq3 = ldf4(Bs + 36 + quad * 8);

  for (int ip = 0; ip < 16; ++ip) {
    const float* bn = Bs + ((ip < 15) ? ip + 1 : 15) * 64;
    f4v bn0 = ldf4(bn + quad * 8);
    f4v bn1 = ldf4(bn + quad * 8 + 4);
    f4v bn2 = ldf4(bn + 32 + quad * 8);
    f4v bn3 = ldf4(bn + 36 + quad * 8);

    // ---- X fragment: X[q=mm][f] = relu(A+B'), K32 A/B-operand layout ----
    s8v x0 = cvt8(relu4(af0 + bq0), relu4(af1 + bq1));
    s8v x1 = cvt8(relu4(af2 + bq2), relu4(af3 + bq3));

    // ---- layer 1 + direct layer 2 (no LDS between) ----
    s4v pk[4];
#pragma unroll
    for (int gt = 0; gt < 4; ++gt) {
      f4v a = c1i[gt];
      a = __builtin_amdgcn_mfma_f32_16x16x32_bf16(W1f[gt][0], x0, a, 0, 0, 0);
      a = __builtin_amdgcn_mfma_f32_16x16x32_bf16(W1f[gt][1], x1, a, 0, 0, 0);
      // lane: Y1[g=gt*16+quad*4+r][q=mm] == K16 B-operand frag
      pk[gt] = cvt4(relu4(a));
    }
#pragma unroll
    for (int ot = 0; ot < 4; ++ot) {
      f4v a = c2i[ot];
      a = MFMA16(W2f[ot][0], pk[0], a);
      a = MFMA16(W2f[ot][1], pk[1], a);
      a = MFMA16(W2f[ot][2], pk[2], a);
      a = MFMA16(W2f[ot][3], pk[3], a);
      cs[ot] += relu4(a);    // lane: o = ot*16+quad*4+r, q = mm
    }

    bq0 = bn0; bq1 = bn1; bq2 = bn2; bq3 = bn3;
  }

  // ---- reduce over q (mm lanes) -> per-wave LDS slice (NO atomics) ----
#pragma unroll
  for (int ot = 0; ot < 4; ++ot) {
#pragma unroll
    for (int r = 0; r < 4; ++r) {
      float v = cs[ot][r];
      v += __shfl_xor(v, 1);
      v += __shfl_xor(v, 2);
      v += __shfl_xor(v, 4);
      v += __shfl_xor(v, 8);
      if (mm == 0) WaveS[wid * 64 + ot * 16 + quad * 4 + r] = v;
    }
  }
  __syncthreads();
  if (t < 64) {
    float s = WaveS[t] + WaveS[64 + t] + WaveS[128 + t] + WaveS[192 + t];
    Part[(b * 64 + blkx) * 64 + t] = s;   // distinct slot, no contention
  }
}

// ---------------------------------------------------------------------------
// Kernel 3: reduce 64 partials per (b,o), then f-network. grid 16 x 256.
// ---------------------------------------------------------------------------
__global__ __launch_bounds__(256) void k_final(
    const float* __restrict__ Part, const float* __restrict__ Wp,
    const float* __restrict__ bp, const float* __restrict__ Wo,
    const float* __restrict__ bo, float* __restrict__ out) {
  __shared__ float red[4][64];
  __shared__ float sv[64], tv[64];
  const int b = blockIdx.x, t = threadIdx.x;
  const int o = t & 63, jw = t >> 6;
  const float* Pb = Part + b * 64 * 64;
  float s = 0.f;
#pragma unroll
  for (int j = 0; j < 16; ++j) s += Pb[(jw * 16 + j) * 64 + o];  // coalesced
  red[jw][o] = s;
  __syncthreads();
  if (t < 64) sv[t] = red[0][t] + red[1][t] + red[2][t] + red[3][t];
  __syncthreads();
  if (t < 64) {
    float acc = bp[t];
#pragma unroll
    for (int g4 = 0; g4 < 16; ++g4) {
      f4v wv = ldf4(Wp + t * 64 + g4 * 4);
      f4v xv = ldf4(sv + g4 * 4);
      acc += wv[0] * xv[0] + wv[1] * xv[1] + wv[2] * xv[2] + wv[3] * xv[3];
    }
    tv[t] = fmaxf(acc, 0.f);
  }
  __syncthreads();
  if (t < 64) {
    float o2 = bo[t];
#pragma unroll
    for (int g4 = 0; g4 < 16; ++g4) {
      f4v wv = ldf4(Wo + t * 64 + g4 * 4);
      f4v xv = ldf4(tv + g4 * 4);
      o2 += wv[0] * xv[0] + wv[1] * xv[1] + wv[2] * xv[2] + wv[3] * xv[3];
    }
    out[b * 64 + t] = o2;
  }
}

// ---------------------------------------------------------------------------
extern "C" void kernel_launch(void* const* d_in, const int* in_sizes, int n_in,
                              void* d_out, int out_size, void* d_ws, size_t ws_size,
                              hipStream_t stream) {
  const float* x   = (const float*)d_in[0];
  const float* Wg0 = (const float*)d_in[1];
  const float* bg0 = (const float*)d_in[2];
  const float* Wg1 = (const float*)d_in[3];
  const float* bg1 = (const float*)d_in[4];
  const float* Wg2 = (const float*)d_in[5];
  const float* bg2 = (const float*)d_in[6];
  const float* Wp  = (const float*)d_in[7];
  const float* bp  = (const float*)d_in[8];
  const float* Wo  = (const float*)d_in[9];
  const float* bo  = (const float*)d_in[10];
  float* out = (float*)d_out;

  float* Ag   = (float*)d_ws;            // [16][256][64] fp32 = 1 MB
  float* Bg   = Ag + 16 * 256 * 64;      // [16][256][64] fp32 = 1 MB
  float* Part = Bg + 16 * 256 * 64;      // [16][64][64] fp32 = 256 KB

  k_pre<<<256, 256, 0, stream>>>(x, Wg0, bg0, Ag, Bg);
  k_main<<<dim3(64, 16), 256, 0, stream>>>(Ag, Bg, Wg1, bg1, Wg2, bg2, Part);
  k_final<<<16, 256, 0, stream>>>(Part, Wp, bp, Wo, bo, out);
}

// Round 3
// 116.166 us; speedup vs baseline: 2.3122x; 1.4845x over previous
//
#include <hip/hip_runtime.h>

// ---------------------------------------------------------------------------
// BatchRelationalModule: b=16, c=64, L=256, F=64
// Round 9: FIX THE SPILL. Round 8's __launch_bounds__(256,4) capped the
// allocator at VGPR=64; the ~130 KEEP-pinned live registers spilled to
// scratch: FETCH 117MB + WRITE 42MB per k_main dispatch => 99us memory
// thrash (vs ~20KB/block ideal). Restore (256,2): compiler's natural
// allocation is ~104 VGPR (verified r6/r7-phaseB), which the HW already
// runs at 4 waves/SIMD (104*4=416<=512) => grid 1024 gives 4 blocks/CU
// co-resident WITHOUT any register cap. Same 2x-latency-hiding goal as r8,
// zero spill. k_final keeps the 256-thread vectorized form.
// ---------------------------------------------------------------------------

typedef short s8v __attribute__((ext_vector_type(8)));   // 8 x bf16 (4 VGPR)
typedef short s4v __attribute__((ext_vector_type(4)));   // 4 x bf16 (2 VGPR)
typedef float f4v __attribute__((ext_vector_type(4)));   // 4 x f32  (4 VGPR)

#define KEEP(x) asm volatile("" : "+v"(x))   // opaque: forbids remat/sink

#define MFMA16(a, b, c) __builtin_amdgcn_mfma_f32_16x16x16bf16_1k(a, b, c, 0, 0, 0)

__device__ __forceinline__ short bfr(float v) {
  return __builtin_bit_cast(short, (__bf16)v);           // fp32 -> bf16 (RNE)
}
__device__ __forceinline__ f4v relu4(f4v v) {
  f4v z = {0.f, 0.f, 0.f, 0.f};
  return __builtin_elementwise_max(v, z);
}
__device__ __forceinline__ s8v cvt8(f4v a, f4v b) {
  s8v r;
  r[0] = bfr(a[0]); r[1] = bfr(a[1]); r[2] = bfr(a[2]); r[3] = bfr(a[3]);
  r[4] = bfr(b[0]); r[5] = bfr(b[1]); r[6] = bfr(b[2]); r[7] = bfr(b[3]);
  return r;
}
__device__ __forceinline__ s4v cvt4(f4v a) {
  s4v r;
  r[0] = bfr(a[0]); r[1] = bfr(a[1]); r[2] = bfr(a[2]); r[3] = bfr(a[3]);
  return r;
}
__device__ __forceinline__ f4v ldf4(const float* p) {
  return *(const f4v*)p;
}

// ---------------------------------------------------------------------------
// Kernel 1: precompute A and B' (fp32). Unchanged (verified).
// ---------------------------------------------------------------------------
__global__ __launch_bounds__(256) void k_pre(
    const float* __restrict__ x, const float* __restrict__ Wg0,
    const float* __restrict__ bg0, float* __restrict__ Ag,
    float* __restrict__ Bg) {
  __shared__ float ws[64 * 131];
  __shared__ float xs[64 * 17];

  const int t = threadIdx.x;
  const int b = blockIdx.x >> 4;
  const int l0 = (blockIdx.x & 15) * 16;

  for (int i = t; i < 64 * 130; i += 256) {
    int f = i / 130, d = i - f * 130;
    ws[f * 131 + d] = Wg0[i];
  }
  for (int i = t; i < 64 * 16; i += 256) {
    int ch = i >> 4, li = i & 15;
    xs[ch * 17 + li] = x[b * 16384 + ch * 256 + l0 + li];
  }
  __syncthreads();

  const int f = t & 63;
  const int w = t >> 6;
  float accA[4] = {0.f, 0.f, 0.f, 0.f};
  float accB[4] = {0.f, 0.f, 0.f, 0.f};
  for (int d = 0; d < 64; ++d) {
    float wa = ws[f * 131 + d];
    float wb = ws[f * 131 + 65 + d];
#pragma unroll
    for (int i = 0; i < 4; ++i) {
      float xv = xs[d * 17 + w + 4 * i];
      accA[i] += xv * wa;
      accB[i] += xv * wb;
    }
  }
  const float wca = ws[f * 131 + 64];
  const float wcb = ws[f * 131 + 129];
  const float bias = bg0[f];
#pragma unroll
  for (int i = 0; i < 4; ++i) {
    int l = l0 + w + 4 * i;
    Ag[(b * 256 + l) * 64 + f] = accA[i] + (float)l * wca;
    Bg[(b * 256 + l) * 64 + f] = accB[i] + (float)l * wcb + bias;
  }
}

// ---------------------------------------------------------------------------
// Kernel 2: pair loop. grid (64, 16) x 256 thr = 1024 blocks; VGPR ~104 =>
// HW occupancy 4 waves/SIMD => 4 blocks/CU co-resident (2x round-6's
// latency hiding). 16 p-rows per block. launch_bounds (256,2): do NOT cap
// the allocator harder (r8 lesson: (256,4) => VGPR=64 => full spill).
// ---------------------------------------------------------------------------
__global__ __launch_bounds__(256, 2) void k_main(
    const float* __restrict__ Ag, const float* __restrict__ Bg,
    const float* __restrict__ Wg1, const float* __restrict__ bg1,
    const float* __restrict__ Wg2, const float* __restrict__ bg2,
    float* __restrict__ Part) {
  __shared__ __align__(16) float Bs[16 * 64];   // 4 KB
  __shared__ float WaveS[4 * 64];               // 1 KB

  const int t = threadIdx.x;
  const int wid = t >> 6;
  const int lane = t & 63;
  const int mm = lane & 15;
  const int quad = lane >> 4;
  const int b = blockIdx.y;
  const int blkx = blockIdx.x;          // 0..63
  const int qq = blkx & 3;
  const int p0 = (blkx >> 2) * 16;      // 16 p-groups of 16 rows
  const int q0 = (qq * 4 + wid) * 16;

  // ---- stage B'[16 rows] (4 KB) into LDS, coalesced dwordx4 ----
  {
    const f4v* Bb4 = (const f4v*)(Bg + (b * 256 + p0) * 64);
    ((f4v*)Bs)[t] = Bb4[t];
  }

  // ---- A rows pinned: A[q0+mm][f = kh*32 + quad*8 + j] ----
  const float* Arow = Ag + (b * 256 + q0 + mm) * 64;
  f4v af0 = ldf4(Arow + quad * 8);
  f4v af1 = ldf4(Arow + quad * 8 + 4);
  f4v af2 = ldf4(Arow + 32 + quad * 8);
  f4v af3 = ldf4(Arow + 36 + quad * 8);

  // ---- layer-1 weights, K32 A-operand: W1[gt*16+mm][kh*32+quad*8+j] ----
  s8v W1f[4][2];
  // ---- layer-2 weights, K16 A-operand: W2[ot*16+mm][gt*16+quad*4+i] ----
  s4v W2f[4][4];
  f4v c1i[4], c2i[4];
#pragma unroll
  for (int gt = 0; gt < 4; ++gt) {
    c1i[gt] = ldf4(bg1 + gt * 16 + quad * 4);
    c2i[gt] = ldf4(bg2 + gt * 16 + quad * 4);
#pragma unroll
    for (int kh = 0; kh < 2; ++kh) {
      const float* r1 = Wg1 + (gt * 16 + mm) * 64 + kh * 32 + quad * 8;
      W1f[gt][kh] = cvt8(ldf4(r1), ldf4(r1 + 4));
    }
#pragma unroll
    for (int kt = 0; kt < 4; ++kt) {
      const float* r2 = Wg2 + (gt * 16 + mm) * 64 + kt * 16 + quad * 4;
      W2f[gt][kt] = cvt4(ldf4(r2));
    }
  }
  // Pin loop-invariants in registers (defeat remat/sink).
#pragma unroll
  for (int gt = 0; gt < 4; ++gt) {
    KEEP(W1f[gt][0]); KEEP(W1f[gt][1]);
    KEEP(W2f[gt][0]); KEEP(W2f[gt][1]); KEEP(W2f[gt][2]); KEEP(W2f[gt][3]);
    KEEP(c1i[gt]); KEEP(c2i[gt]);
  }
  KEEP(af0); KEEP(af1); KEEP(af2); KEEP(af3);

  __syncthreads();   // Bs staged

  f4v cs[4] = {{0.f,0.f,0.f,0.f},{0.f,0.f,0.f,0.f},
               {0.f,0.f,0.f,0.f},{0.f,0.f,0.f,0.f}};

  // prefetch B'-frag for p = p0 (quad-broadcast ds_read_b128)
  f4v bq0 = ldf4(Bs + quad * 8);
  f4v bq1 = ldf4(Bs + quad * 8 + 4);
  f4v bq2 = ldf4(Bs + 32 + quad * 8);
  f4v bq3 = ldf4(Bs + 36 + quad * 8);

  for (int ip = 0; ip < 16; ++ip) {
    const float* bn = Bs + ((ip < 15) ? ip + 1 : 15) * 64;
    f4v bn0 = ldf4(bn + quad * 8);
    f4v bn1 = ldf4(bn + quad * 8 + 4);
    f4v bn2 = ldf4(bn + 32 + quad * 8);
    f4v bn3 = ldf4(bn + 36 + quad * 8);

    // ---- X fragment: X[q=mm][f] = relu(A+B'), K32 A/B-operand layout ----
    s8v x0 = cvt8(relu4(af0 + bq0), relu4(af1 + bq1));
    s8v x1 = cvt8(relu4(af2 + bq2), relu4(af3 + bq3));

    // ---- layer 1 + direct layer 2 (no LDS between) ----
    s4v pk[4];
#pragma unroll
    for (int gt = 0; gt < 4; ++gt) {
      f4v a = c1i[gt];
      a = __builtin_amdgcn_mfma_f32_16x16x32_bf16(W1f[gt][0], x0, a, 0, 0, 0);
      a = __builtin_amdgcn_mfma_f32_16x16x32_bf16(W1f[gt][1], x1, a, 0, 0, 0);
      // lane: Y1[g=gt*16+quad*4+r][q=mm] == K16 B-operand frag
      pk[gt] = cvt4(relu4(a));
    }
#pragma unroll
    for (int ot = 0; ot < 4; ++ot) {
      f4v a = c2i[ot];
      a = MFMA16(W2f[ot][0], pk[0], a);
      a = MFMA16(W2f[ot][1], pk[1], a);
      a = MFMA16(W2f[ot][2], pk[2], a);
      a = MFMA16(W2f[ot][3], pk[3], a);
      cs[ot] += relu4(a);    // lane: o = ot*16+quad*4+r, q = mm
    }

    bq0 = bn0; bq1 = bn1; bq2 = bn2; bq3 = bn3;
  }

  // ---- reduce over q (mm lanes) -> per-wave LDS slice (NO atomics) ----
#pragma unroll
  for (int ot = 0; ot < 4; ++ot) {
#pragma unroll
    for (int r = 0; r < 4; ++r) {
      float v = cs[ot][r];
      v += __shfl_xor(v, 1);
      v += __shfl_xor(v, 2);
      v += __shfl_xor(v, 4);
      v += __shfl_xor(v, 8);
      if (mm == 0) WaveS[wid * 64 + ot * 16 + quad * 4 + r] = v;
    }
  }
  __syncthreads();
  if (t < 64) {
    float s = WaveS[t] + WaveS[64 + t] + WaveS[128 + t] + WaveS[192 + t];
    Part[(b * 64 + blkx) * 64 + t] = s;   // distinct slot, no contention
  }
}

// ---------------------------------------------------------------------------
// Kernel 3: reduce 64 partials per (b,o), then f-network. grid 16 x 256.
// ---------------------------------------------------------------------------
__global__ __launch_bounds__(256) void k_final(
    const float* __restrict__ Part, const float* __restrict__ Wp,
    const float* __restrict__ bp, const float* __restrict__ Wo,
    const float* __restrict__ bo, float* __restrict__ out) {
  __shared__ float red[4][64];
  __shared__ float sv[64], tv[64];
  const int b = blockIdx.x, t = threadIdx.x;
  const int o = t & 63, jw = t >> 6;
  const float* Pb = Part + b * 64 * 64;
  float s = 0.f;
#pragma unroll
  for (int j = 0; j < 16; ++j) s += Pb[(jw * 16 + j) * 64 + o];  // coalesced
  red[jw][o] = s;
  __syncthreads();
  if (t < 64) sv[t] = red[0][t] + red[1][t] + red[2][t] + red[3][t];
  __syncthreads();
  if (t < 64) {
    float acc = bp[t];
#pragma unroll
    for (int g4 = 0; g4 < 16; ++g4) {
      f4v wv = ldf4(Wp + t * 64 + g4 * 4);
      f4v xv = ldf4(sv + g4 * 4);
      acc += wv[0] * xv[0] + wv[1] * xv[1] + wv[2] * xv[2] + wv[3] * xv[3];
    }
    tv[t] = fmaxf(acc, 0.f);
  }
  __syncthreads();
  if (t < 64) {
    float o2 = bo[t];
#pragma unroll
    for (int g4 = 0; g4 < 16; ++g4) {
      f4v wv = ldf4(Wo + t * 64 + g4 * 4);
      f4v xv = ldf4(tv + g4 * 4);
      o2 += wv[0] * xv[0] + wv[1] * xv[1] + wv[2] * xv[2] + wv[3] * xv[3];
    }
    out[b * 64 + t] = o2;
  }
}

// ---------------------------------------------------------------------------
extern "C" void kernel_launch(void* const* d_in, const int* in_sizes, int n_in,
                              void* d_out, int out_size, void* d_ws, size_t ws_size,
                              hipStream_t stream) {
  const float* x   = (const float*)d_in[0];
  const float* Wg0 = (const float*)d_in[1];
  const float* bg0 = (const float*)d_in[2];
  const float* Wg1 = (const float*)d_in[3];
  const float* bg1 = (const float*)d_in[4];
  const float* Wg2 = (const float*)d_in[5];
  const float* bg2 = (const float*)d_in[6];
  const float* Wp  = (const float*)d_in[7];
  const float* bp  = (const float*)d_in[8];
  const float* Wo  = (const float*)d_in[9];
  const float* bo  = (const float*)d_in[10];
  float* out = (float*)d_out;

  float* Ag   = (float*)d_ws;            // [16][256][64] fp32 = 1 MB
  float* Bg   = Ag + 16 * 256 * 64;      // [16][256][64] fp32 = 1 MB
  float* Part = Bg + 16 * 256 * 64;      // [16][64][64] fp32 = 256 KB

  k_pre<<<256, 256, 0, stream>>>(x, Wg0, bg0, Ag, Bg);
  k_main<<<dim3(64, 16), 256, 0, stream>>>(Ag, Bg, Wg1, bg1, Wg2, bg2, Part);
  k_final<<<16, 256, 0, stream>>>(Part, Wp, bp, Wo, bo, out);
}